// Round 1
// baseline (1168.804 us; speedup 1.0000x reference)
//
#include <hip/hip_runtime.h>
#include <math.h>

#define THREADS 256
#define SEQ 2048
#define DMODEL 1024
#define NHEADS 8
#define HDIM 128
#define MROWS 4096  // B*S

// =====================================================================
// QKV projection: C = x @ W^T, x[4096][1024], W[1024][1024] row-major.
// NT GEMM: both A and B read along rows (K contiguous) -> coalesced.
// Output written head-major: [B, H, S, Hd] so attention reads are linear.
// 64x64 tile, BK=32, 256 threads, 4x4 microtile, k-major LDS (pad->68:
// keeps float4 LDS reads 16B-aligned; read banking is 2-way = free).
// =====================================================================
__global__ __launch_bounds__(THREADS)
void gemm_qkv(const float* __restrict__ x,
              const float* __restrict__ Wq, const float* __restrict__ Wk,
              const float* __restrict__ Wv,
              float* __restrict__ qo, float* __restrict__ ko,
              float* __restrict__ vo)
{
    __shared__ float As[32][68];
    __shared__ float Bs[32][68];
    const int t  = threadIdx.x;
    const int tx = t & 15, ty = t >> 4;
    const int m0 = blockIdx.y << 6;
    const int n0 = blockIdx.x << 6;
    const float* __restrict__ W = (blockIdx.z == 0) ? Wq : (blockIdx.z == 1) ? Wk : Wv;
    float* __restrict__ O       = (blockIdx.z == 0) ? qo : (blockIdx.z == 1) ? ko : vo;

    const int lrow = t >> 3;        // 0..31
    const int lk   = (t & 7) << 2;  // 0,4,...,28

    const float* ap0 = x + (size_t)(m0 + lrow) * DMODEL + lk;
    const float* ap1 = ap0 + (size_t)32 * DMODEL;
    const float* bp0 = W + (size_t)(n0 + lrow) * DMODEL + lk;
    const float* bp1 = bp0 + (size_t)32 * DMODEL;

    float acc[4][4] = {};

    for (int kt = 0; kt < DMODEL; kt += 32) {
        float4 a0 = *(const float4*)(ap0 + kt);
        float4 a1 = *(const float4*)(ap1 + kt);
        float4 b0 = *(const float4*)(bp0 + kt);
        float4 b1 = *(const float4*)(bp1 + kt);
        __syncthreads();            // prior iteration's LDS reads done
        As[lk+0][lrow] = a0.x; As[lk+1][lrow] = a0.y; As[lk+2][lrow] = a0.z; As[lk+3][lrow] = a0.w;
        As[lk+0][lrow+32] = a1.x; As[lk+1][lrow+32] = a1.y; As[lk+2][lrow+32] = a1.z; As[lk+3][lrow+32] = a1.w;
        Bs[lk+0][lrow] = b0.x; Bs[lk+1][lrow] = b0.y; Bs[lk+2][lrow] = b0.z; Bs[lk+3][lrow] = b0.w;
        Bs[lk+0][lrow+32] = b1.x; Bs[lk+1][lrow+32] = b1.y; Bs[lk+2][lrow+32] = b1.z; Bs[lk+3][lrow+32] = b1.w;
        __syncthreads();
        #pragma unroll 8
        for (int k = 0; k < 32; ++k) {
            float4 av = *(const float4*)&As[k][ty << 2];
            float4 bv = *(const float4*)&Bs[k][tx << 2];
            float a_[4] = {av.x, av.y, av.z, av.w};
            float b_[4] = {bv.x, bv.y, bv.z, bv.w};
            #pragma unroll
            for (int i = 0; i < 4; ++i)
                #pragma unroll
                for (int j = 0; j < 4; ++j)
                    acc[i][j] = fmaf(a_[i], b_[j], acc[i][j]);
        }
    }

    // store, remapping col n = h*128+hd into [B,H,S,Hd]; block spans one head
    const int h   = n0 >> 7;
    const int hd0 = (n0 & 127) + (tx << 2);
    #pragma unroll
    for (int i = 0; i < 4; ++i) {
        int m = m0 + (ty << 2) + i;
        int b = m >> 11, s = m & 2047;
        float4 vv = make_float4(acc[i][0], acc[i][1], acc[i][2], acc[i][3]);
        size_t off = (((size_t)((b << 3) | h) * SEQ + s) << 7) + hd0;
        *(float4*)&O[off] = vv;
    }
}

// =====================================================================
// Output projection: C = A @ Wu^T + bu, A = attn output [4096][1024].
// =====================================================================
__global__ __launch_bounds__(THREADS)
void gemm_out(const float* __restrict__ A, const float* __restrict__ Wu,
              const float* __restrict__ bu, float* __restrict__ C)
{
    __shared__ float As[32][68];
    __shared__ float Bs[32][68];
    const int t  = threadIdx.x;
    const int tx = t & 15, ty = t >> 4;
    const int m0 = blockIdx.y << 6;
    const int n0 = blockIdx.x << 6;

    const int lrow = t >> 3;
    const int lk   = (t & 7) << 2;

    const float* ap0 = A + (size_t)(m0 + lrow) * DMODEL + lk;
    const float* ap1 = ap0 + (size_t)32 * DMODEL;
    const float* bp0 = Wu + (size_t)(n0 + lrow) * DMODEL + lk;
    const float* bp1 = bp0 + (size_t)32 * DMODEL;

    float acc[4][4] = {};

    for (int kt = 0; kt < DMODEL; kt += 32) {
        float4 a0 = *(const float4*)(ap0 + kt);
        float4 a1 = *(const float4*)(ap1 + kt);
        float4 b0 = *(const float4*)(bp0 + kt);
        float4 b1 = *(const float4*)(bp1 + kt);
        __syncthreads();
        As[lk+0][lrow] = a0.x; As[lk+1][lrow] = a0.y; As[lk+2][lrow] = a0.z; As[lk+3][lrow] = a0.w;
        As[lk+0][lrow+32] = a1.x; As[lk+1][lrow+32] = a1.y; As[lk+2][lrow+32] = a1.z; As[lk+3][lrow+32] = a1.w;
        Bs[lk+0][lrow] = b0.x; Bs[lk+1][lrow] = b0.y; Bs[lk+2][lrow] = b0.z; Bs[lk+3][lrow] = b0.w;
        Bs[lk+0][lrow+32] = b1.x; Bs[lk+1][lrow+32] = b1.y; Bs[lk+2][lrow+32] = b1.z; Bs[lk+3][lrow+32] = b1.w;
        __syncthreads();
        #pragma unroll 8
        for (int k = 0; k < 32; ++k) {
            float4 av = *(const float4*)&As[k][ty << 2];
            float4 bv = *(const float4*)&Bs[k][tx << 2];
            float a_[4] = {av.x, av.y, av.z, av.w};
            float b_[4] = {bv.x, bv.y, bv.z, bv.w};
            #pragma unroll
            for (int i = 0; i < 4; ++i)
                #pragma unroll
                for (int j = 0; j < 4; ++j)
                    acc[i][j] = fmaf(a_[i], b_[j], acc[i][j]);
        }
    }

    const int n = n0 + (tx << 2);
    float4 bias = *(const float4*)&bu[n];
    #pragma unroll
    for (int i = 0; i < 4; ++i) {
        int m = m0 + (ty << 2) + i;
        float4 vv = make_float4(acc[i][0] + bias.x, acc[i][1] + bias.y,
                                acc[i][2] + bias.z, acc[i][3] + bias.w);
        *(float4*)&C[(size_t)m * DMODEL + n] = vv;
    }
}

// =====================================================================
// Flash attention fwd, fp32, non-causal. One block = 64 q-rows of one
// (b,h). Q persistent in LDS (hd-major), 32-key tiles; K-chunk and the
// P matrix share one LDS union buffer. Per-head weight fused at the end.
// LDS: 34816 + 16896 + 9216 = 60928 B -> 2 blocks/CU, grid 512 = 2/CU.
// =====================================================================
#define KTILE 32

__global__ __launch_bounds__(THREADS)
void attn_fwd(const float* __restrict__ Q, const float* __restrict__ K,
              const float* __restrict__ V, const float* __restrict__ hw,
              float* __restrict__ O)
{
    __shared__ float Qs[128][68];     // Q tile transposed: Qs[hd][q]
    __shared__ float Vs[KTILE][132];  // V tile row-major
    __shared__ float U[64 * 36];      // union: Ks[64][36] / Ps[32][68]

    const int t  = threadIdx.x;
    const int tx = t & 15, ty = t >> 4;
    const int bh = blockIdx.y;        // b*8 + h
    const int q0 = blockIdx.x << 6;
    const size_t base = (size_t)bh * SEQ * HDIM;
    const float* Qp = Q + base;
    const float* Kp = K + base;
    const float* Vp = V + base;

    // load Q tile, transposed into LDS
    {
        const int qr = t >> 5;          // 0..7
        const int hd = (t & 31) << 2;   // 0..124
        #pragma unroll
        for (int p = 0; p < 8; ++p) {
            float4 qv = *(const float4*)&Qp[(size_t)(q0 + qr + p * 8) * HDIM + hd];
            Qs[hd+0][qr + p*8] = qv.x;
            Qs[hd+1][qr + p*8] = qv.y;
            Qs[hd+2][qr + p*8] = qv.z;
            Qs[hd+3][qr + p*8] = qv.w;
        }
    }

    float o_acc[4][8] = {};
    float m_run[4], l_run[4];
    #pragma unroll
    for (int i = 0; i < 4; ++i) { m_run[i] = -1e30f; l_run[i] = 0.f; }

    const float scale = 0.08838834764831845f;  // 128^-0.5

    const int vkk = t >> 5;           // 0..7
    const int vhd = (t & 31) << 2;    // 0..124
    const int kkk = t >> 4;           // 0..15
    const int khd = (t & 15) << 2;    // 0..60

    for (int kt = 0; kt < SEQ; kt += KTILE) {
        // prefetch V tile + K chunk 0 to registers
        float4 vr[4];
        #pragma unroll
        for (int p = 0; p < 4; ++p)
            vr[p] = *(const float4*)&Vp[(size_t)(kt + vkk + p * 8) * HDIM + vhd];
        float4 kr[2];
        #pragma unroll
        for (int p = 0; p < 2; ++p)
            kr[p] = *(const float4*)&Kp[(size_t)(kt + kkk + p * 16) * HDIM + khd];

        __syncthreads();   // prior tile's Vs / U(Ps) reads complete
        #pragma unroll
        for (int p = 0; p < 4; ++p)
            *(float4*)&Vs[vkk + p * 8][vhd] = vr[p];
        #pragma unroll
        for (int p = 0; p < 2; ++p) {
            U[(khd+0)*36 + kkk + p*16] = kr[p].x;
            U[(khd+1)*36 + kkk + p*16] = kr[p].y;
            U[(khd+2)*36 + kkk + p*16] = kr[p].z;
            U[(khd+3)*36 + kkk + p*16] = kr[p].w;
        }
        __syncthreads();

        float s_reg[4][2] = {};
        // ---- scores chunk 0: hd 0..63 ----
        #pragma unroll 8
        for (int hd = 0; hd < 64; ++hd) {
            float4 qv = *(const float4*)&Qs[hd][ty << 2];
            float2 kv = *(const float2*)&U[hd * 36 + (tx << 1)];
            s_reg[0][0] = fmaf(qv.x, kv.x, s_reg[0][0]);
            s_reg[0][1] = fmaf(qv.x, kv.y, s_reg[0][1]);
            s_reg[1][0] = fmaf(qv.y, kv.x, s_reg[1][0]);
            s_reg[1][1] = fmaf(qv.y, kv.y, s_reg[1][1]);
            s_reg[2][0] = fmaf(qv.z, kv.x, s_reg[2][0]);
            s_reg[2][1] = fmaf(qv.z, kv.y, s_reg[2][1]);
            s_reg[3][0] = fmaf(qv.w, kv.x, s_reg[3][0]);
            s_reg[3][1] = fmaf(qv.w, kv.y, s_reg[3][1]);
        }
        // ---- scores chunk 1: hd 64..127 ----
        #pragma unroll
        for (int p = 0; p < 2; ++p)
            kr[p] = *(const float4*)&Kp[(size_t)(kt + kkk + p * 16) * HDIM + 64 + khd];
        __syncthreads();   // chunk-0 Ks reads done
        #pragma unroll
        for (int p = 0; p < 2; ++p) {
            U[(khd+0)*36 + kkk + p*16] = kr[p].x;
            U[(khd+1)*36 + kkk + p*16] = kr[p].y;
            U[(khd+2)*36 + kkk + p*16] = kr[p].z;
            U[(khd+3)*36 + kkk + p*16] = kr[p].w;
        }
        __syncthreads();
        #pragma unroll 8
        for (int hd = 0; hd < 64; ++hd) {
            float4 qv = *(const float4*)&Qs[64 + hd][ty << 2];
            float2 kv = *(const float2*)&U[hd * 36 + (tx << 1)];
            s_reg[0][0] = fmaf(qv.x, kv.x, s_reg[0][0]);
            s_reg[0][1] = fmaf(qv.x, kv.y, s_reg[0][1]);
            s_reg[1][0] = fmaf(qv.y, kv.x, s_reg[1][0]);
            s_reg[1][1] = fmaf(qv.y, kv.y, s_reg[1][1]);
            s_reg[2][0] = fmaf(qv.z, kv.x, s_reg[2][0]);
            s_reg[2][1] = fmaf(qv.z, kv.y, s_reg[2][1]);
            s_reg[3][0] = fmaf(qv.w, kv.x, s_reg[3][0]);
            s_reg[3][1] = fmaf(qv.w, kv.y, s_reg[3][1]);
        }

        // ---- online softmax (per q-row; 16-lane tx-group reductions) ----
        float p_reg[4][2];
        float alpha[4];
        #pragma unroll
        for (int i = 0; i < 4; ++i) {
            float s0 = s_reg[i][0] * scale;
            float s1 = s_reg[i][1] * scale;
            float mx = fmaxf(s0, s1);
            #pragma unroll
            for (int off = 1; off < 16; off <<= 1)
                mx = fmaxf(mx, __shfl_xor(mx, off));
            float mnew = fmaxf(m_run[i], mx);
            float p0 = __expf(s0 - mnew);
            float p1 = __expf(s1 - mnew);
            float rs = p0 + p1;
            #pragma unroll
            for (int off = 1; off < 16; off <<= 1)
                rs += __shfl_xor(rs, off);
            alpha[i]  = __expf(m_run[i] - mnew);
            l_run[i]  = l_run[i] * alpha[i] + rs;
            m_run[i]  = mnew;
            p_reg[i][0] = p0;
            p_reg[i][1] = p1;
        }
        #pragma unroll
        for (int i = 0; i < 4; ++i)
            #pragma unroll
            for (int j = 0; j < 8; ++j)
                o_acc[i][j] *= alpha[i];

        __syncthreads();   // Ks chunk-1 reads done before P overwrites U
        // Ps[kk][q], stride 68 (16B-aligned float4 reads)
        #pragma unroll
        for (int i = 0; i < 4; ++i) {
            U[((tx << 1) + 0) * 68 + (ty << 2) + i] = p_reg[i][0];
            U[((tx << 1) + 1) * 68 + (ty << 2) + i] = p_reg[i][1];
        }
        __syncthreads();

        // ---- PV: O[q][hd] += P[q][kk] * V[kk][hd] ----
        #pragma unroll 4
        for (int kk = 0; kk < KTILE; ++kk) {
            float4 pv = *(const float4*)&U[kk * 68 + (ty << 2)];
            float4 v0 = *(const float4*)&Vs[kk][(tx << 3)];
            float4 v1 = *(const float4*)&Vs[kk][(tx << 3) + 4];
            float pp[4] = {pv.x, pv.y, pv.z, pv.w};
            float vv[8] = {v0.x, v0.y, v0.z, v0.w, v1.x, v1.y, v1.z, v1.w};
            #pragma unroll
            for (int i = 0; i < 4; ++i)
                #pragma unroll
                for (int j = 0; j < 8; ++j)
                    o_acc[i][j] = fmaf(pp[i], vv[j], o_acc[i][j]);
        }
    }

    // ---- epilogue: /l, *head_weight, store into [B,S,D] layout ----
    const float w = hw[bh & 7];
    const int b = bh >> 3;
    const int h = bh & 7;
    #pragma unroll
    for (int i = 0; i < 4; ++i) {
        float f = w / l_run[i];
        int qrow = q0 + (ty << 2) + i;
        float4 r0 = make_float4(o_acc[i][0]*f, o_acc[i][1]*f, o_acc[i][2]*f, o_acc[i][3]*f);
        float4 r1 = make_float4(o_acc[i][4]*f, o_acc[i][5]*f, o_acc[i][6]*f, o_acc[i][7]*f);
        size_t off = ((size_t)(b * SEQ + qrow) * DMODEL) + h * HDIM + (tx << 3);
        *(float4*)&O[off]     = r0;
        *(float4*)&O[off + 4] = r1;
    }
}

// =====================================================================
extern "C" void kernel_launch(void* const* d_in, const int* in_sizes, int n_in,
                              void* d_out, int out_size, void* d_ws, size_t ws_size,
                              hipStream_t stream) {
    const float* x  = (const float*)d_in[0];
    const float* Wq = (const float*)d_in[1];
    const float* Wk = (const float*)d_in[2];
    const float* Wv = (const float*)d_in[3];
    const float* hw = (const float*)d_in[4];
    const float* Wu = (const float*)d_in[5];
    const float* bu = (const float*)d_in[6];
    float* out = (float*)d_out;

    const size_t MD = (size_t)MROWS * DMODEL;  // 4,194,304 elements
    float* q_ws = (float*)d_ws;
    float* k_ws = q_ws + MD;
    float* v_ws = k_ws + MD;
    float* a_ws = v_ws + MD;   // attention output, [B,S,D] layout

    dim3 blk(THREADS);

    // 1) Q,K,V projections (head-major outputs)
    dim3 g1(DMODEL / 64, MROWS / 64, 3);
    gemm_qkv<<<g1, blk, 0, stream>>>(x, Wq, Wk, Wv, q_ws, k_ws, v_ws);

    // 2) attention + per-head reweight
    dim3 g2(SEQ / 64, 2 * NHEADS);
    attn_fwd<<<g2, blk, 0, stream>>>(q_ws, k_ws, v_ws, hw, a_ws);

    // 3) output projection + bias
    dim3 g3(DMODEL / 64, MROWS / 64);
    gemm_out<<<g3, blk, 0, stream>>>(a_ws, Wu, bu, out);
}

// Round 2
// 894.892 us; speedup vs baseline: 1.3061x; 1.3061x over previous
//
#include <hip/hip_runtime.h>
#include <hip/hip_bf16.h>
#include <math.h>

#define THREADS 256
#define SEQ 2048
#define DMODEL 1024
#define NHEADS 8
#define HDIM 128
#define MROWS 4096  // B*S

typedef __attribute__((ext_vector_type(8))) short short8;
typedef __attribute__((ext_vector_type(4))) float f32x4;

// async global->LDS, 16B per lane. LDS dest is wave-uniform base + lane*16.
#define GLOAD16(gp, lp) __builtin_amdgcn_global_load_lds( \
    (const __attribute__((address_space(1))) void*)(gp),  \
    (__attribute__((address_space(3))) void*)(lp), 16, 0, 0)

__device__ __forceinline__ void splitf(float f, unsigned short& h, unsigned short& l) {
    __hip_bfloat16 bh = __float2bfloat16(f);
    float fh = __bfloat162float(bh);
    __hip_bfloat16 bl = __float2bfloat16(f - fh);
    h = *(unsigned short*)&bh;
    l = *(unsigned short*)&bl;
}

// =====================================================================
// split_all: fp32 -> (bf16 hi, bf16 lo) for x, Wq, Wk, Wv, Wu.
// 8M elems total, 8 per thread, 1M threads.
// =====================================================================
__global__ __launch_bounds__(256)
void split_all(const float* __restrict__ x, const float* __restrict__ wq,
               const float* __restrict__ wk, const float* __restrict__ wv,
               const float* __restrict__ wu,
               unsigned short* __restrict__ xh, unsigned short* __restrict__ xl,
               unsigned short* __restrict__ wqh, unsigned short* __restrict__ wql,
               unsigned short* __restrict__ wkh, unsigned short* __restrict__ wkl,
               unsigned short* __restrict__ wvh, unsigned short* __restrict__ wvl,
               unsigned short* __restrict__ wuh, unsigned short* __restrict__ wul)
{
    const size_t e = ((size_t)blockIdx.x * 256 + threadIdx.x) << 3;
    const size_t XN = (size_t)MROWS * DMODEL;  // 4M
    const float* src; unsigned short *dh, *dl; size_t off;
    if (e < XN) { src = x; dh = xh; dl = xl; off = e; }
    else {
        size_t r = e - XN;
        int seg = (int)(r >> 20);
        off = r & 1048575;
        switch (seg) {
            case 0:  src = wq; dh = wqh; dl = wql; break;
            case 1:  src = wk; dh = wkh; dl = wkl; break;
            case 2:  src = wv; dh = wvh; dl = wvl; break;
            default: src = wu; dh = wuh; dl = wul; break;
        }
    }
    float4 f0 = *(const float4*)(src + off);
    float4 f1 = *(const float4*)(src + off + 4);
    float fs[8] = {f0.x, f0.y, f0.z, f0.w, f1.x, f1.y, f1.z, f1.w};
    union { unsigned short u[8]; uint4 v; } H, L;
    #pragma unroll
    for (int j = 0; j < 8; ++j) splitf(fs[j], H.u[j], L.u[j]);
    *(uint4*)&dh[off] = H.v;
    *(uint4*)&dl[off] = L.v;
}

// =====================================================================
// Split-bf16 MFMA NT GEMM core: C[128x128] = A @ B^T over virtual
// K' = 3072: phase0 Ah@Bh, phase1 Ah@Bl, phase2 Al@Bh.
// BK=64, 4 waves (2x2), wave tile 64x64 = 4x4 mfma_f32_16x16x32_bf16.
// LDS tiles [128 rows][64 bf16] with XOR slot swizzle (slot ^= row&7):
// written linearly by global_load_lds from inverse-swizzled global addrs,
// read as swizzled ds_read_b128 -> ~2-way banking (free).
// =====================================================================
__device__ __forceinline__ void gemm_split_core(
    const unsigned short* __restrict__ Ah, const unsigned short* __restrict__ Al,
    const unsigned short* __restrict__ Bh, const unsigned short* __restrict__ Bl,
    int m0, int n0, unsigned short* As, unsigned short* Bs, f32x4 acc[4][4])
{
    const int t = threadIdx.x, lane = t & 63, w = t >> 6;
    const int wr = w >> 1, wc = w & 1;
    const int rl  = lane >> 3;                       // row within 8-row group
    const int sg8 = ((lane & 7) ^ (rl & 7)) << 3;    // inverse-swizzled global slot (elems)
    const int fr = lane & 15, fg = lane >> 4;

    #pragma unroll
    for (int mi = 0; mi < 4; ++mi)
        #pragma unroll
        for (int nj = 0; nj < 4; ++nj)
            acc[mi][nj] = (f32x4){0.f, 0.f, 0.f, 0.f};

    #pragma unroll 1
    for (int T = 0; T < 48; ++T) {
        const int p  = T >> 4;
        const int kc = (T & 15) << 6;
        const unsigned short* Asrc = (p < 2 ? Ah : Al) + kc + sg8;
        const unsigned short* Bsrc = (p == 1 ? Bl : Bh) + kc + sg8;
        __syncthreads();                  // prior tile's LDS reads done
        #pragma unroll
        for (int j = 0; j < 4; ++j) {
            const int rb = (w << 3) + (j << 5);      // wave-uniform row base
            GLOAD16(Asrc + (size_t)(m0 + rb + rl) * DMODEL, &As[rb << 6]);
            GLOAD16(Bsrc + (size_t)(n0 + rb + rl) * DMODEL, &Bs[rb << 6]);
        }
        __syncthreads();                  // drains vmcnt then barrier
        #pragma unroll
        for (int ks = 0; ks < 2; ++ks) {
            short8 av[4], bv[4];
            #pragma unroll
            for (int mi = 0; mi < 4; ++mi)
                av[mi] = *(const short8*)&As[(((wr << 6) + (mi << 4) + fr) << 6)
                                             + ((((ks << 2) + fg) ^ (fr & 7)) << 3)];
            #pragma unroll
            for (int nj = 0; nj < 4; ++nj)
                bv[nj] = *(const short8*)&Bs[(((wc << 6) + (nj << 4) + fr) << 6)
                                             + ((((ks << 2) + fg) ^ (fr & 7)) << 3)];
            #pragma unroll
            for (int mi = 0; mi < 4; ++mi)
                #pragma unroll
                for (int nj = 0; nj < 4; ++nj)
                    acc[mi][nj] = __builtin_amdgcn_mfma_f32_16x16x32_bf16(
                        av[mi], bv[nj], acc[mi][nj], 0, 0, 0);
        }
    }
}

// QKV projection via split MFMA; writes q/k/v fp32 head-major [B,H,S,Hd].
// BN=128 == head width, so head h == blockIdx.x.
__global__ __launch_bounds__(THREADS)
void gemm_qkv_mfma(const unsigned short* __restrict__ xh, const unsigned short* __restrict__ xl,
                   const unsigned short* __restrict__ wqh, const unsigned short* __restrict__ wql,
                   const unsigned short* __restrict__ wkh, const unsigned short* __restrict__ wkl,
                   const unsigned short* __restrict__ wvh, const unsigned short* __restrict__ wvl,
                   float* __restrict__ qo, float* __restrict__ ko, float* __restrict__ vo)
{
    __shared__ unsigned short As[128 * 64];
    __shared__ unsigned short Bs[128 * 64];
    const int z = blockIdx.z;
    const unsigned short* Bh = (z == 0) ? wqh : (z == 1) ? wkh : wvh;
    const unsigned short* Bl = (z == 0) ? wql : (z == 1) ? wkl : wvl;
    float* __restrict__ O    = (z == 0) ? qo : (z == 1) ? ko : vo;
    const int m0 = blockIdx.y << 7, n0 = blockIdx.x << 7;

    f32x4 acc[4][4];
    gemm_split_core(xh, xl, Bh, Bl, m0, n0, As, Bs, acc);

    const int lane = threadIdx.x & 63, w = threadIdx.x >> 6;
    const int wr = w >> 1, wc = w & 1, fr = lane & 15, fg = lane >> 4;
    const int h = blockIdx.x;
    #pragma unroll
    for (int mi = 0; mi < 4; ++mi)
        #pragma unroll
        for (int nj = 0; nj < 4; ++nj) {
            const int hd = (wc << 6) + (nj << 4) + fr;
            #pragma unroll
            for (int r = 0; r < 4; ++r) {
                int m = m0 + (wr << 6) + (mi << 4) + (fg << 2) + r;
                int b = m >> 11, s = m & 2047;
                O[((((size_t)(b << 3) | h) * SEQ + s) << 7) + hd] = acc[mi][nj][r];
            }
        }
}

// Output projection via split MFMA + bias; C[4096][1024] fp32.
__global__ __launch_bounds__(THREADS)
void gemm_out_mfma(const unsigned short* __restrict__ ah, const unsigned short* __restrict__ al,
                   const unsigned short* __restrict__ wuh, const unsigned short* __restrict__ wul,
                   const float* __restrict__ bu, float* __restrict__ C)
{
    __shared__ unsigned short As[128 * 64];
    __shared__ unsigned short Bs[128 * 64];
    const int m0 = blockIdx.y << 7, n0 = blockIdx.x << 7;

    f32x4 acc[4][4];
    gemm_split_core(ah, al, wuh, wul, m0, n0, As, Bs, acc);

    const int lane = threadIdx.x & 63, w = threadIdx.x >> 6;
    const int wr = w >> 1, wc = w & 1, fr = lane & 15, fg = lane >> 4;
    #pragma unroll
    for (int mi = 0; mi < 4; ++mi)
        #pragma unroll
        for (int nj = 0; nj < 4; ++nj) {
            const int n = n0 + (wc << 6) + (nj << 4) + fr;
            const float bias = bu[n];
            #pragma unroll
            for (int r = 0; r < 4; ++r) {
                int m = m0 + (wr << 6) + (mi << 4) + (fg << 2) + r;
                C[(size_t)m * DMODEL + n] = acc[mi][nj][r] + bias;
            }
        }
}

// =====================================================================
// Flash attention fwd, fp32 (unchanged core from round 1).
// attn_fwd_split: epilogue emits split bf16 (hi/lo) for the out-GEMM.
// attn_fwd_f32:   round-1 fallback writing fp32.
// =====================================================================
#define KTILE 32

#define ATTN_BODY                                                                      \
    __shared__ float Qs[128][68];                                                      \
    __shared__ float Vs[KTILE][132];                                                   \
    __shared__ float U[64 * 36];                                                       \
    const int t  = threadIdx.x;                                                        \
    const int tx = t & 15, ty = t >> 4;                                                \
    const int bh = blockIdx.y;                                                         \
    const int q0 = blockIdx.x << 6;                                                    \
    const size_t base = (size_t)bh * SEQ * HDIM;                                       \
    const float* Qp = Q + base;                                                        \
    const float* Kp = K + base;                                                        \
    const float* Vp = V + base;                                                        \
    {                                                                                  \
        const int qr = t >> 5;                                                         \
        const int hd = (t & 31) << 2;                                                  \
        _Pragma("unroll")                                                              \
        for (int p = 0; p < 8; ++p) {                                                  \
            float4 qv = *(const float4*)&Qp[(size_t)(q0 + qr + p * 8) * HDIM + hd];    \
            Qs[hd+0][qr + p*8] = qv.x;                                                 \
            Qs[hd+1][qr + p*8] = qv.y;                                                 \
            Qs[hd+2][qr + p*8] = qv.z;                                                 \
            Qs[hd+3][qr + p*8] = qv.w;                                                 \
        }                                                                              \
    }                                                                                  \
    float o_acc[4][8] = {};                                                            \
    float m_run[4], l_run[4];                                                          \
    _Pragma("unroll")                                                                  \
    for (int i = 0; i < 4; ++i) { m_run[i] = -1e30f; l_run[i] = 0.f; }                 \
    const float scale = 0.08838834764831845f;                                          \
    const int vkk = t >> 5;                                                            \
    const int vhd = (t & 31) << 2;                                                     \
    const int kkk = t >> 4;                                                            \
    const int khd = (t & 15) << 2;                                                     \
    for (int kt = 0; kt < SEQ; kt += KTILE) {                                          \
        float4 vr[4];                                                                  \
        _Pragma("unroll")                                                              \
        for (int p = 0; p < 4; ++p)                                                    \
            vr[p] = *(const float4*)&Vp[(size_t)(kt + vkk + p * 8) * HDIM + vhd];      \
        float4 kr[2];                                                                  \
        _Pragma("unroll")                                                              \
        for (int p = 0; p < 2; ++p)                                                    \
            kr[p] = *(const float4*)&Kp[(size_t)(kt + kkk + p * 16) * HDIM + khd];     \
        __syncthreads();                                                               \
        _Pragma("unroll")                                                              \
        for (int p = 0; p < 4; ++p)                                                    \
            *(float4*)&Vs[vkk + p * 8][vhd] = vr[p];                                   \
        _Pragma("unroll")                                                              \
        for (int p = 0; p < 2; ++p) {                                                  \
            U[(khd+0)*36 + kkk + p*16] = kr[p].x;                                      \
            U[(khd+1)*36 + kkk + p*16] = kr[p].y;                                      \
            U[(khd+2)*36 + kkk + p*16] = kr[p].z;                                      \
            U[(khd+3)*36 + kkk + p*16] = kr[p].w;                                      \
        }                                                                              \
        __syncthreads();                                                               \
        float s_reg[4][2] = {};                                                        \
        _Pragma("unroll 8")                                                            \
        for (int hd = 0; hd < 64; ++hd) {                                              \
            float4 qv = *(const float4*)&Qs[hd][ty << 2];                              \
            float2 kv = *(const float2*)&U[hd * 36 + (tx << 1)];                       \
            s_reg[0][0] = fmaf(qv.x, kv.x, s_reg[0][0]);                               \
            s_reg[0][1] = fmaf(qv.x, kv.y, s_reg[0][1]);                               \
            s_reg[1][0] = fmaf(qv.y, kv.x, s_reg[1][0]);                               \
            s_reg[1][1] = fmaf(qv.y, kv.y, s_reg[1][1]);                               \
            s_reg[2][0] = fmaf(qv.z, kv.x, s_reg[2][0]);                               \
            s_reg[2][1] = fmaf(qv.z, kv.y, s_reg[2][1]);                               \
            s_reg[3][0] = fmaf(qv.w, kv.x, s_reg[3][0]);                               \
            s_reg[3][1] = fmaf(qv.w, kv.y, s_reg[3][1]);                               \
        }                                                                              \
        _Pragma("unroll")                                                              \
        for (int p = 0; p < 2; ++p)                                                    \
            kr[p] = *(const float4*)&Kp[(size_t)(kt + kkk + p * 16) * HDIM + 64 + khd];\
        __syncthreads();                                                               \
        _Pragma("unroll")                                                              \
        for (int p = 0; p < 2; ++p) {                                                  \
            U[(khd+0)*36 + kkk + p*16] = kr[p].x;                                      \
            U[(khd+1)*36 + kkk + p*16] = kr[p].y;                                      \
            U[(khd+2)*36 + kkk + p*16] = kr[p].z;                                      \
            U[(khd+3)*36 + kkk + p*16] = kr[p].w;                                      \
        }                                                                              \
        __syncthreads();                                                               \
        _Pragma("unroll 8")                                                            \
        for (int hd = 0; hd < 64; ++hd) {                                              \
            float4 qv = *(const float4*)&Qs[64 + hd][ty << 2];                         \
            float2 kv = *(const float2*)&U[hd * 36 + (tx << 1)];                       \
            s_reg[0][0] = fmaf(qv.x, kv.x, s_reg[0][0]);                               \
            s_reg[0][1] = fmaf(qv.x, kv.y, s_reg[0][1]);                               \
            s_reg[1][0] = fmaf(qv.y, kv.x, s_reg[1][0]);                               \
            s_reg[1][1] = fmaf(qv.y, kv.y, s_reg[1][1]);                               \
            s_reg[2][0] = fmaf(qv.z, kv.x, s_reg[2][0]);                               \
            s_reg[2][1] = fmaf(qv.z, kv.y, s_reg[2][1]);                               \
            s_reg[3][0] = fmaf(qv.w, kv.x, s_reg[3][0]);                               \
            s_reg[3][1] = fmaf(qv.w, kv.y, s_reg[3][1]);                               \
        }                                                                              \
        float p_reg[4][2];                                                             \
        float alpha[4];                                                                \
        _Pragma("unroll")                                                              \
        for (int i = 0; i < 4; ++i) {                                                  \
            float s0 = s_reg[i][0] * scale;                                            \
            float s1 = s_reg[i][1] * scale;                                            \
            float mx = fmaxf(s0, s1);                                                  \
            _Pragma("unroll")                                                          \
            for (int off = 1; off < 16; off <<= 1)                                     \
                mx = fmaxf(mx, __shfl_xor(mx, off));                                   \
            float mnew = fmaxf(m_run[i], mx);                                          \
            float p0 = __expf(s0 - mnew);                                              \
            float p1 = __expf(s1 - mnew);                                              \
            float rs = p0 + p1;                                                        \
            _Pragma("unroll")                                                          \
            for (int off = 1; off < 16; off <<= 1)                                     \
                rs += __shfl_xor(rs, off);                                             \
            alpha[i]  = __expf(m_run[i] - mnew);                                       \
            l_run[i]  = l_run[i] * alpha[i] + rs;                                      \
            m_run[i]  = mnew;                                                          \
            p_reg[i][0] = p0;                                                          \
            p_reg[i][1] = p1;                                                          \
        }                                                                              \
        _Pragma("unroll")                                                              \
        for (int i = 0; i < 4; ++i)                                                    \
            _Pragma("unroll")                                                          \
            for (int j = 0; j < 8; ++j)                                                \
                o_acc[i][j] *= alpha[i];                                               \
        __syncthreads();                                                               \
        _Pragma("unroll")                                                              \
        for (int i = 0; i < 4; ++i) {                                                  \
            U[((tx << 1) + 0) * 68 + (ty << 2) + i] = p_reg[i][0];                     \
            U[((tx << 1) + 1) * 68 + (ty << 2) + i] = p_reg[i][1];                     \
        }                                                                              \
        __syncthreads();                                                               \
        _Pragma("unroll 4")                                                            \
        for (int kk = 0; kk < KTILE; ++kk) {                                           \
            float4 pv = *(const float4*)&U[kk * 68 + (ty << 2)];                       \
            float4 v0 = *(const float4*)&Vs[kk][(tx << 3)];                            \
            float4 v1 = *(const float4*)&Vs[kk][(tx << 3) + 4];                        \
            float pp[4] = {pv.x, pv.y, pv.z, pv.w};                                    \
            float vv[8] = {v0.x, v0.y, v0.z, v0.w, v1.x, v1.y, v1.z, v1.w};            \
            _Pragma("unroll")                                                          \
            for (int i = 0; i < 4; ++i)                                                \
                _Pragma("unroll")                                                      \
                for (int j = 0; j < 8; ++j)                                            \
                    o_acc[i][j] = fmaf(pp[i], vv[j], o_acc[i][j]);                     \
        }                                                                              \
    }

__global__ __launch_bounds__(THREADS)
void attn_fwd_split(const float* __restrict__ Q, const float* __restrict__ K,
                    const float* __restrict__ V, const float* __restrict__ hw,
                    unsigned short* __restrict__ a_hi, unsigned short* __restrict__ a_lo)
{
    ATTN_BODY
    const float wgt = hw[bh & 7];
    const int b = bh >> 3;
    const int h = bh & 7;
    #pragma unroll
    for (int i = 0; i < 4; ++i) {
        float f = wgt / l_run[i];
        int qrow = q0 + (ty << 2) + i;
        size_t off = ((size_t)(b * SEQ + qrow) * DMODEL) + h * HDIM + (tx << 3);
        union { unsigned short u[8]; uint4 v; } H, L;
        #pragma unroll
        for (int j = 0; j < 8; ++j) splitf(o_acc[i][j] * f, H.u[j], L.u[j]);
        *(uint4*)&a_hi[off] = H.v;
        *(uint4*)&a_lo[off] = L.v;
    }
}

__global__ __launch_bounds__(THREADS)
void attn_fwd_f32(const float* __restrict__ Q, const float* __restrict__ K,
                  const float* __restrict__ V, const float* __restrict__ hw,
                  float* __restrict__ O)
{
    ATTN_BODY
    const float wgt = hw[bh & 7];
    const int b = bh >> 3;
    const int h = bh & 7;
    #pragma unroll
    for (int i = 0; i < 4; ++i) {
        float f = wgt / l_run[i];
        int qrow = q0 + (ty << 2) + i;
        float4 r0 = make_float4(o_acc[i][0]*f, o_acc[i][1]*f, o_acc[i][2]*f, o_acc[i][3]*f);
        float4 r1 = make_float4(o_acc[i][4]*f, o_acc[i][5]*f, o_acc[i][6]*f, o_acc[i][7]*f);
        size_t off = ((size_t)(b * SEQ + qrow) * DMODEL) + h * HDIM + (tx << 3);
        *(float4*)&O[off]     = r0;
        *(float4*)&O[off + 4] = r1;
    }
}

// ======================= round-1 fp32 fallback GEMMs =======================
__global__ __launch_bounds__(THREADS)
void gemm_qkv_f32(const float* __restrict__ x,
                  const float* __restrict__ Wq, const float* __restrict__ Wk,
                  const float* __restrict__ Wv,
                  float* __restrict__ qo, float* __restrict__ ko,
                  float* __restrict__ vo)
{
    __shared__ float As[32][68];
    __shared__ float Bs[32][68];
    const int t  = threadIdx.x;
    const int tx = t & 15, ty = t >> 4;
    const int m0 = blockIdx.y << 6;
    const int n0 = blockIdx.x << 6;
    const float* __restrict__ W = (blockIdx.z == 0) ? Wq : (blockIdx.z == 1) ? Wk : Wv;
    float* __restrict__ O       = (blockIdx.z == 0) ? qo : (blockIdx.z == 1) ? ko : vo;
    const int lrow = t >> 3;
    const int lk   = (t & 7) << 2;
    const float* ap0 = x + (size_t)(m0 + lrow) * DMODEL + lk;
    const float* ap1 = ap0 + (size_t)32 * DMODEL;
    const float* bp0 = W + (size_t)(n0 + lrow) * DMODEL + lk;
    const float* bp1 = bp0 + (size_t)32 * DMODEL;
    float acc[4][4] = {};
    for (int kt = 0; kt < DMODEL; kt += 32) {
        float4 a0 = *(const float4*)(ap0 + kt);
        float4 a1 = *(const float4*)(ap1 + kt);
        float4 b0 = *(const float4*)(bp0 + kt);
        float4 b1 = *(const float4*)(bp1 + kt);
        __syncthreads();
        As[lk+0][lrow] = a0.x; As[lk+1][lrow] = a0.y; As[lk+2][lrow] = a0.z; As[lk+3][lrow] = a0.w;
        As[lk+0][lrow+32] = a1.x; As[lk+1][lrow+32] = a1.y; As[lk+2][lrow+32] = a1.z; As[lk+3][lrow+32] = a1.w;
        Bs[lk+0][lrow] = b0.x; Bs[lk+1][lrow] = b0.y; Bs[lk+2][lrow] = b0.z; Bs[lk+3][lrow] = b0.w;
        Bs[lk+0][lrow+32] = b1.x; Bs[lk+1][lrow+32] = b1.y; Bs[lk+2][lrow+32] = b1.z; Bs[lk+3][lrow+32] = b1.w;
        __syncthreads();
        #pragma unroll 8
        for (int k = 0; k < 32; ++k) {
            float4 av = *(const float4*)&As[k][ty << 2];
            float4 bv = *(const float4*)&Bs[k][tx << 2];
            float a_[4] = {av.x, av.y, av.z, av.w};
            float b_[4] = {bv.x, bv.y, bv.z, bv.w};
            #pragma unroll
            for (int i = 0; i < 4; ++i)
                #pragma unroll
                for (int j = 0; j < 4; ++j)
                    acc[i][j] = fmaf(a_[i], b_[j], acc[i][j]);
        }
    }
    const int h   = n0 >> 7;
    const int hd0 = (n0 & 127) + (tx << 2);
    #pragma unroll
    for (int i = 0; i < 4; ++i) {
        int m = m0 + (ty << 2) + i;
        int b = m >> 11, s = m & 2047;
        float4 vv = make_float4(acc[i][0], acc[i][1], acc[i][2], acc[i][3]);
        size_t off = (((size_t)((b << 3) | h) * SEQ + s) << 7) + hd0;
        *(float4*)&O[off] = vv;
    }
}

__global__ __launch_bounds__(THREADS)
void gemm_out_f32(const float* __restrict__ A, const float* __restrict__ Wu,
                  const float* __restrict__ bu, float* __restrict__ C)
{
    __shared__ float As[32][68];
    __shared__ float Bs[32][68];
    const int t  = threadIdx.x;
    const int tx = t & 15, ty = t >> 4;
    const int m0 = blockIdx.y << 6;
    const int n0 = blockIdx.x << 6;
    const int lrow = t >> 3;
    const int lk   = (t & 7) << 2;
    const float* ap0 = A + (size_t)(m0 + lrow) * DMODEL + lk;
    const float* ap1 = ap0 + (size_t)32 * DMODEL;
    const float* bp0 = Wu + (size_t)(n0 + lrow) * DMODEL + lk;
    const float* bp1 = bp0 + (size_t)32 * DMODEL;
    float acc[4][4] = {};
    for (int kt = 0; kt < DMODEL; kt += 32) {
        float4 a0 = *(const float4*)(ap0 + kt);
        float4 a1 = *(const float4*)(ap1 + kt);
        float4 b0 = *(const float4*)(bp0 + kt);
        float4 b1 = *(const float4*)(bp1 + kt);
        __syncthreads();
        As[lk+0][lrow] = a0.x; As[lk+1][lrow] = a0.y; As[lk+2][lrow] = a0.z; As[lk+3][lrow] = a0.w;
        As[lk+0][lrow+32] = a1.x; As[lk+1][lrow+32] = a1.y; As[lk+2][lrow+32] = a1.z; As[lk+3][lrow+32] = a1.w;
        Bs[lk+0][lrow] = b0.x; Bs[lk+1][lrow] = b0.y; Bs[lk+2][lrow] = b0.z; Bs[lk+3][lrow] = b0.w;
        Bs[lk+0][lrow+32] = b1.x; Bs[lk+1][lrow+32] = b1.y; Bs[lk+2][lrow+32] = b1.z; Bs[lk+3][lrow+32] = b1.w;
        __syncthreads();
        #pragma unroll 8
        for (int k = 0; k < 32; ++k) {
            float4 av = *(const float4*)&As[k][ty << 2];
            float4 bv = *(const float4*)&Bs[k][tx << 2];
            float a_[4] = {av.x, av.y, av.z, av.w};
            float b_[4] = {bv.x, bv.y, bv.z, bv.w};
            #pragma unroll
            for (int i = 0; i < 4; ++i)
                #pragma unroll
                for (int j = 0; j < 4; ++j)
                    acc[i][j] = fmaf(a_[i], b_[j], acc[i][j]);
        }
    }
    const int n = n0 + (tx << 2);
    float4 bias = *(const float4*)&bu[n];
    #pragma unroll
    for (int i = 0; i < 4; ++i) {
        int m = m0 + (ty << 2) + i;
        float4 vv = make_float4(acc[i][0] + bias.x, acc[i][1] + bias.y,
                                acc[i][2] + bias.z, acc[i][3] + bias.w);
        *(float4*)&C[(size_t)m * DMODEL + n] = vv;
    }
}

// =====================================================================
extern "C" void kernel_launch(void* const* d_in, const int* in_sizes, int n_in,
                              void* d_out, int out_size, void* d_ws, size_t ws_size,
                              hipStream_t stream) {
    const float* x  = (const float*)d_in[0];
    const float* Wq = (const float*)d_in[1];
    const float* Wk = (const float*)d_in[2];
    const float* Wv = (const float*)d_in[3];
    const float* hw = (const float*)d_in[4];
    const float* Wu = (const float*)d_in[5];
    const float* bu = (const float*)d_in[6];
    float* out = (float*)d_out;

    const size_t MD = (size_t)MROWS * DMODEL;   // 4M elems
    const size_t WN = (size_t)DMODEL * DMODEL;  // 1M elems
    dim3 blk(THREADS);

    if (ws_size >= (size_t)84 * 1024 * 1024) {
        // ---- split-bf16 MFMA path (needs 80 MB ws) ----
        float* q_ws = (float*)d_ws;               // 16 MB
        float* k_ws = q_ws + MD;                  // 16 MB
        float* v_ws = k_ws + MD;                  // 16 MB
        unsigned short* xh = (unsigned short*)(v_ws + MD);  // 8 MB
        unsigned short* xl = xh + MD;                       // 8 MB
        unsigned short* wqh = xl + MD;            // 8 x 2 MB
        unsigned short* wql = wqh + WN;
        unsigned short* wkh = wql + WN;
        unsigned short* wkl = wkh + WN;
        unsigned short* wvh = wkl + WN;
        unsigned short* wvl = wvh + WN;
        unsigned short* wuh = wvl + WN;
        unsigned short* wul = wuh + WN;
        unsigned short* a_hi = xh;  // alias: x splits dead after gemm_qkv
        unsigned short* a_lo = xl;

        split_all<<<dim3(4096), blk, 0, stream>>>(x, Wq, Wk, Wv, Wu,
            xh, xl, wqh, wql, wkh, wkl, wvh, wvl, wuh, wul);
        gemm_qkv_mfma<<<dim3(NHEADS, MROWS / 128, 3), blk, 0, stream>>>(
            xh, xl, wqh, wql, wkh, wkl, wvh, wvl, q_ws, k_ws, v_ws);
        attn_fwd_split<<<dim3(SEQ / 64, 2 * NHEADS), blk, 0, stream>>>(
            q_ws, k_ws, v_ws, hw, a_hi, a_lo);
        gemm_out_mfma<<<dim3(DMODEL / 128, MROWS / 128), blk, 0, stream>>>(
            a_hi, a_lo, wuh, wul, bu, out);
    } else {
        // ---- round-1 fp32 fallback (64 MB ws) ----
        float* q_ws = (float*)d_ws;
        float* k_ws = q_ws + MD;
        float* v_ws = k_ws + MD;
        float* a_ws = v_ws + MD;
        gemm_qkv_f32<<<dim3(DMODEL / 64, MROWS / 64, 3), blk, 0, stream>>>(
            x, Wq, Wk, Wv, q_ws, k_ws, v_ws);
        attn_fwd_f32<<<dim3(SEQ / 64, 2 * NHEADS), blk, 0, stream>>>(
            q_ws, k_ws, v_ws, hw, a_ws);
        gemm_out_f32<<<dim3(DMODEL / 64, MROWS / 64), blk, 0, stream>>>(
            a_ws, Wu, bu, out);
    }
}

// Round 10
// 346.900 us; speedup vs baseline: 3.3693x; 2.5797x over previous
//
#include <hip/hip_runtime.h>
#include <hip/hip_bf16.h>
#include <math.h>

#define THREADS 256
#define SEQ 2048
#define DMODEL 1024
#define NHEADS 8
#define HDIM 128
#define MROWS 4096  // B*S

typedef __attribute__((ext_vector_type(8))) short short8;
typedef __attribute__((ext_vector_type(4))) float f32x4;

// async global->LDS, 16B per lane. LDS dest is wave-uniform base + lane*16.
#define GLOAD16(gp, lp) __builtin_amdgcn_global_load_lds( \
    (const __attribute__((address_space(1))) void*)(gp),  \
    (__attribute__((address_space(3))) void*)(lp), 16, 0, 0)

__device__ __forceinline__ void splitf(float f, unsigned short& h, unsigned short& l) {
    __hip_bfloat16 bh = __float2bfloat16(f);
    float fh = __bfloat162float(bh);
    __hip_bfloat16 bl = __float2bfloat16(f - fh);
    h = *(unsigned short*)&bh;
    l = *(unsigned short*)&bl;
}

__device__ __forceinline__ unsigned short bf16of(float f) {
    __hip_bfloat16 b = __float2bfloat16(f);
    return *(unsigned short*)&b;
}

// =====================================================================
// split_all: fp32 -> (bf16 hi, bf16 lo) for x, Wq, Wk, Wv, Wu.
// =====================================================================
__global__ __launch_bounds__(256)
void split_all(const float* __restrict__ x, const float* __restrict__ wq,
               const float* __restrict__ wk, const float* __restrict__ wv,
               const float* __restrict__ wu,
               unsigned short* __restrict__ xh, unsigned short* __restrict__ xl,
               unsigned short* __restrict__ wqh, unsigned short* __restrict__ wql,
               unsigned short* __restrict__ wkh, unsigned short* __restrict__ wkl,
               unsigned short* __restrict__ wvh, unsigned short* __restrict__ wvl,
               unsigned short* __restrict__ wuh, unsigned short* __restrict__ wul)
{
    const size_t e = ((size_t)blockIdx.x * 256 + threadIdx.x) << 3;
    const size_t XN = (size_t)MROWS * DMODEL;  // 4M
    const float* src; unsigned short *dh, *dl; size_t off;
    if (e < XN) { src = x; dh = xh; dl = xl; off = e; }
    else {
        size_t r = e - XN;
        int seg = (int)(r >> 20);
        off = r & 1048575;
        switch (seg) {
            case 0:  src = wq; dh = wqh; dl = wql; break;
            case 1:  src = wk; dh = wkh; dl = wkl; break;
            case 2:  src = wv; dh = wvh; dl = wvl; break;
            default: src = wu; dh = wuh; dl = wul; break;
        }
    }
    float4 f0 = *(const float4*)(src + off);
    float4 f1 = *(const float4*)(src + off + 4);
    float fs[8] = {f0.x, f0.y, f0.z, f0.w, f1.x, f1.y, f1.z, f1.w};
    union { unsigned short u[8]; uint4 v; } H, L;
    #pragma unroll
    for (int j = 0; j < 8; ++j) splitf(fs[j], H.u[j], L.u[j]);
    *(uint4*)&dh[off] = H.v;
    *(uint4*)&dl[off] = L.v;
}

// =====================================================================
// Split-bf16 MFMA NT GEMM core (validated round 2): C[128x128] = A @ B^T
// over virtual K'=3072: Ah@Bh, Ah@Bl, Al@Bh. BK=64, 4 waves 2x2, each
// 4x4 of mfma_f32_16x16x32_bf16. XOR-swizzled LDS, gload_lds width 16.
// =====================================================================
__device__ __forceinline__ void gemm_split_core(
    const unsigned short* __restrict__ Ah, const unsigned short* __restrict__ Al,
    const unsigned short* __restrict__ Bh, const unsigned short* __restrict__ Bl,
    int m0, int n0, unsigned short* As, unsigned short* Bs, f32x4 acc[4][4])
{
    const int t = threadIdx.x, lane = t & 63, w = t >> 6;
    const int wr = w >> 1, wc = w & 1;
    const int rl  = lane >> 3;
    const int sg8 = ((lane & 7) ^ (rl & 7)) << 3;
    const int fr = lane & 15, fg = lane >> 4;

    #pragma unroll
    for (int mi = 0; mi < 4; ++mi)
        #pragma unroll
        for (int nj = 0; nj < 4; ++nj)
            acc[mi][nj] = (f32x4){0.f, 0.f, 0.f, 0.f};

    #pragma unroll 1
    for (int T = 0; T < 48; ++T) {
        const int p  = T >> 4;
        const int kc = (T & 15) << 6;
        const unsigned short* Asrc = (p < 2 ? Ah : Al) + kc + sg8;
        const unsigned short* Bsrc = (p == 1 ? Bl : Bh) + kc + sg8;
        __syncthreads();
        #pragma unroll
        for (int j = 0; j < 4; ++j) {
            const int rb = (w << 3) + (j << 5);
            GLOAD16(Asrc + (size_t)(m0 + rb + rl) * DMODEL, &As[rb << 6]);
            GLOAD16(Bsrc + (size_t)(n0 + rb + rl) * DMODEL, &Bs[rb << 6]);
        }
        __syncthreads();
        #pragma unroll
        for (int ks = 0; ks < 2; ++ks) {
            short8 av[4], bv[4];
            #pragma unroll
            for (int mi = 0; mi < 4; ++mi)
                av[mi] = *(const short8*)&As[(((wr << 6) + (mi << 4) + fr) << 6)
                                             + ((((ks << 2) + fg) ^ (fr & 7)) << 3)];
            #pragma unroll
            for (int nj = 0; nj < 4; ++nj)
                bv[nj] = *(const short8*)&Bs[(((wc << 6) + (nj << 4) + fr) << 6)
                                             + ((((ks << 2) + fg) ^ (fr & 7)) << 3)];
            #pragma unroll
            for (int mi = 0; mi < 4; ++mi)
                #pragma unroll
                for (int nj = 0; nj < 4; ++nj)
                    acc[mi][nj] = __builtin_amdgcn_mfma_f32_16x16x32_bf16(
                        av[mi], bv[nj], acc[mi][nj], 0, 0, 0);
        }
    }
}

// =====================================================================
// QKV projections -> bf16 outputs for attention.
// z=0 (Q), z=1 (K): head-major [b,h,s,hd].
// z=2 (V): SWAPPED gemm (C^T = Wv @ x^T) -> transposed [b,h,hd,s].
// =====================================================================
__global__ __launch_bounds__(THREADS)
void gemm_qkv_mfma(const unsigned short* __restrict__ xh, const unsigned short* __restrict__ xl,
                   const unsigned short* __restrict__ wqh, const unsigned short* __restrict__ wql,
                   const unsigned short* __restrict__ wkh, const unsigned short* __restrict__ wkl,
                   const unsigned short* __restrict__ wvh, const unsigned short* __restrict__ wvl,
                   unsigned short* __restrict__ qo, unsigned short* __restrict__ ko,
                   unsigned short* __restrict__ vto)
{
    __shared__ unsigned short As[128 * 64];
    __shared__ unsigned short Bs[128 * 64];
    const int z = blockIdx.z;
    const int lane = threadIdx.x & 63, w = threadIdx.x >> 6;
    const int wr = w >> 1, wc = w & 1, fr = lane & 15, fg = lane >> 4;
    f32x4 acc[4][4];

    if (z < 2) {
        const unsigned short* Bh = z ? wkh : wqh;
        const unsigned short* Bl = z ? wkl : wql;
        unsigned short* O = z ? ko : qo;
        const int m0 = blockIdx.y << 7, n0 = blockIdx.x << 7;
        gemm_split_core(xh, xl, Bh, Bl, m0, n0, As, Bs, acc);
        const int h = blockIdx.x;
        #pragma unroll
        for (int mi = 0; mi < 4; ++mi)
            #pragma unroll
            for (int nj = 0; nj < 4; ++nj) {
                const int hd = (wc << 6) + (nj << 4) + fr;
                #pragma unroll
                for (int r = 0; r < 4; ++r) {
                    int m = m0 + (wr << 6) + (mi << 4) + (fg << 2) + r;
                    int b = m >> 11, s = m & 2047;
                    O[(((size_t)((b << 3) | h) * SEQ + s) << 7) + hd] = bf16of(acc[mi][nj][r]);
                }
            }
    } else {
        // swapped: A = Wv (rows = out dim), B = x (rows = tokens)
        const int m0 = blockIdx.x << 7, n0 = blockIdx.y << 7;
        gemm_split_core(wvh, wvl, xh, xl, m0, n0, As, Bs, acc);
        const int h = blockIdx.x;  // m0 = h*128
        #pragma unroll
        for (int mi = 0; mi < 4; ++mi)
            #pragma unroll
            for (int nj = 0; nj < 4; ++nj) {
                #pragma unroll
                for (int r = 0; r < 4; ++r) {
                    int mfull = m0 + (wr << 6) + (mi << 4) + (fg << 2) + r;  // h*128+hd
                    int nfull = n0 + (wc << 6) + (nj << 4) + fr;            // b*2048+s
                    int hd = mfull & 127;
                    int b = nfull >> 11, s = nfull & 2047;
                    vto[(((size_t)((b << 3) | h) * HDIM + hd) << 11) + s] = bf16of(acc[mi][nj][r]);
                }
            }
    }
}

// =====================================================================
// Output projection (split-bf16, validated round 2) + bias -> fp32 out.
// =====================================================================
__global__ __launch_bounds__(THREADS)
void gemm_out_mfma(const unsigned short* __restrict__ ah, const unsigned short* __restrict__ al,
                   const unsigned short* __restrict__ wuh, const unsigned short* __restrict__ wul,
                   const float* __restrict__ bu, float* __restrict__ C)
{
    __shared__ unsigned short As[128 * 64];
    __shared__ unsigned short Bs[128 * 64];
    const int m0 = blockIdx.y << 7, n0 = blockIdx.x << 7;

    f32x4 acc[4][4];
    gemm_split_core(ah, al, wuh, wul, m0, n0, As, Bs, acc);

    const int lane = threadIdx.x & 63, w = threadIdx.x >> 6;
    const int wr = w >> 1, wc = w & 1, fr = lane & 15, fg = lane >> 4;
    #pragma unroll
    for (int mi = 0; mi < 4; ++mi)
        #pragma unroll
        for (int nj = 0; nj < 4; ++nj) {
            const int n = n0 + (wc << 6) + (nj << 4) + fr;
            const float bias = bu[n];
            #pragma unroll
            for (int r = 0; r < 4; ++r) {
                int m = m0 + (wr << 6) + (mi << 4) + (fg << 2) + r;
                C[(size_t)m * DMODEL + n] = acc[mi][nj][r] + bias;
            }
        }
}

// =====================================================================
// Flash attention, bf16 MFMA. 4 waves x 16 q-rows (QBLK=64), KVBLK=64.
// Q frags persistent in registers. K[64][128] and Vt[128][64] staged per
// iter via gload_lds (inverse-swizzled source, (row&7) slot-XOR on read).
// P round-trips through a swizzled LDS tile (wave-local, DS in-order ->
// no barrier). Per-head weight + 1/l + hi/lo split fused in epilogue.
// LDS 40KB. Grid 512 blocks, XCD-chunked so one (b,h)'s K/V stays in L2.
// =====================================================================
__global__ __launch_bounds__(THREADS)
void attn_mfma(const unsigned short* __restrict__ Qg,
               const unsigned short* __restrict__ Kg,
               const unsigned short* __restrict__ Vtg,
               const float* __restrict__ hw,
               unsigned short* __restrict__ a_hi, unsigned short* __restrict__ a_lo)
{
    __shared__ unsigned short Ks[64 * 128];   // [kv][hd], 16 slots/row, swizzled
    __shared__ unsigned short Vs[128 * 64];   // [hd][kv],  8 slots/row, swizzled
    __shared__ unsigned short Ps[64 * 64];    // [q][kv],   8 slots/row, swizzled

    const int t = threadIdx.x, lane = t & 63, w = t >> 6;
    const int fr = lane & 15, fg = lane >> 4;

    // XCD-aware chunked remap: 512 blocks = 8 XCDs x 64; 32-block runs share (b,h)
    const int bid  = blockIdx.x;
    const int orig = ((bid & 7) << 6) + (bid >> 3);
    const int bh = orig >> 5;
    const int q0 = (orig & 31) << 6;

    const size_t base = (size_t)bh * SEQ * HDIM;
    const unsigned short* Kp  = Kg  + base;
    const unsigned short* Vtp = Vtg + base;

    // persistent Q A-frags: row = q0 + w*16 + fr, k-slices ks*32 + fg*8
    short8 qa[4];
    {
        const unsigned short* qrow = Qg + base + (size_t)(q0 + (w << 4) + fr) * HDIM;
        #pragma unroll
        for (int ks = 0; ks < 4; ++ks)
            qa[ks] = *(const short8*)&qrow[(ks << 5) + (fg << 3)];
    }

    f32x4 o_acc[8];
    #pragma unroll
    for (int j = 0; j < 8; ++j) o_acc[j] = (f32x4){0.f, 0.f, 0.f, 0.f};
    float m_run[4], l_run[4];
    #pragma unroll
    for (int r = 0; r < 4; ++r) { m_run[r] = -1e30f; l_run[r] = 0.f; }
    const float scale = 0.08838834764831845f;  // 128^-0.5

    for (int kt = 0; kt < SEQ; kt += 64) {
        __syncthreads();   // prior iter's Ks/Vs reads complete
        // stage K tile: 1024 slots of 16B, 4 rounds x 256 threads
        #pragma unroll
        for (int p = 0; p < 4; ++p) {
            int sid = (p << 8) + t;
            int R = sid >> 4, sl = sid & 15;
            GLOAD16(Kp + (size_t)(kt + R) * HDIM + ((sl ^ (R & 7)) << 3),
                    &Ks[(sid & ~63) << 3]);
        }
        // stage Vt tile: rows = hd (stride SEQ), 8 slots/row
        #pragma unroll
        for (int p = 0; p < 4; ++p) {
            int sid = (p << 8) + t;
            int R = sid >> 3, sl = sid & 7;
            GLOAD16(Vtp + (size_t)R * SEQ + kt + ((sl ^ (R & 7)) << 3),
                    &Vs[(sid & ~63) << 3]);
        }
        __syncthreads();   // vmcnt(0) drain + barrier

        // ---- S = Q K^T (per wave: 16 q-rows x 64 kv) ----
        f32x4 s_acc[4];
        #pragma unroll
        for (int nj = 0; nj < 4; ++nj) s_acc[nj] = (f32x4){0.f, 0.f, 0.f, 0.f};
        #pragma unroll
        for (int ks = 0; ks < 4; ++ks)
            #pragma unroll
            for (int nj = 0; nj < 4; ++nj) {
                const int row = (nj << 4) + fr;
                short8 kb = *(const short8*)&Ks[(row << 7)
                              + ((((ks << 2) + fg) ^ (row & 7)) << 3)];
                s_acc[nj] = __builtin_amdgcn_mfma_f32_16x16x32_bf16(
                    qa[ks], kb, s_acc[nj], 0, 0, 0);
            }

        // ---- online softmax (rows fg*4+r; reduce over 16 fr-lanes) ----
        float alpha[4];
        #pragma unroll
        for (int nj = 0; nj < 4; ++nj) s_acc[nj] = s_acc[nj] * scale;
        #pragma unroll
        for (int r = 0; r < 4; ++r) {
            float mx = fmaxf(fmaxf(s_acc[0][r], s_acc[1][r]),
                             fmaxf(s_acc[2][r], s_acc[3][r]));
            #pragma unroll
            for (int off = 1; off < 16; off <<= 1)
                mx = fmaxf(mx, __shfl_xor(mx, off));
            float mnew = fmaxf(m_run[r], mx);
            float al = __expf(m_run[r] - mnew);
            float rs = 0.f;
            const int row = (w << 4) + (fg << 2) + r;
            #pragma unroll
            for (int nj = 0; nj < 4; ++nj) {
                float p = __expf(s_acc[nj][r] - mnew);
                rs += p;
                const int slot = (nj << 1) + (fr >> 3);
                Ps[(row << 6) + ((slot ^ (row & 7)) << 3) + (fr & 7)] = bf16of(p);
            }
            #pragma unroll
            for (int off = 1; off < 16; off <<= 1)
                rs += __shfl_xor(rs, off);
            l_run[r] = l_run[r] * al + rs;
            m_run[r] = mnew;
            alpha[r] = al;
        }
        {
            f32x4 av = {alpha[0], alpha[1], alpha[2], alpha[3]};
            #pragma unroll
            for (int j = 0; j < 8; ++j) o_acc[j] = o_acc[j] * av;
        }

        // ---- O += P V  (A = P from LDS, B = Vt; wave-local, DS in-order) ----
        #pragma unroll
        for (int ks = 0; ks < 2; ++ks) {
            const int prow = (w << 4) + fr;
            short8 pa = *(const short8*)&Ps[(prow << 6)
                          + ((((ks << 2) + fg) ^ (prow & 7)) << 3)];
            #pragma unroll
            for (int nj = 0; nj < 8; ++nj) {
                const int vrow = (nj << 4) + fr;
                short8 vb = *(const short8*)&Vs[(vrow << 6)
                              + ((((ks << 2) + fg) ^ (vrow & 7)) << 3)];
                o_acc[nj] = __builtin_amdgcn_mfma_f32_16x16x32_bf16(
                    pa, vb, o_acc[nj], 0, 0, 0);
            }
        }
    }

    // ---- epilogue: /l, *head_weight, split hi/lo, store [B,S,D] ----
    const float wgt = hw[bh & 7];
    const int bb = bh >> 3, hh = bh & 7;
    #pragma unroll
    for (int r = 0; r < 4; ++r) {
        const float f = wgt / l_run[r];
        const int q = q0 + (w << 4) + (fg << 2) + r;
        const size_t rowoff = ((size_t)(bb * SEQ + q) * DMODEL) + hh * HDIM + fr;
        #pragma unroll
        for (int j = 0; j < 8; ++j) {
            unsigned short hsv, lsv;
            splitf(o_acc[j][r] * f, hsv, lsv);
            a_hi[rowoff + (j << 4)] = hsv;
            a_lo[rowoff + (j << 4)] = lsv;
        }
    }
}

// =====================================================================
extern "C" void kernel_launch(void* const* d_in, const int* in_sizes, int n_in,
                              void* d_out, int out_size, void* d_ws, size_t ws_size,
                              hipStream_t stream) {
    const float* x  = (const float*)d_in[0];
    const float* Wq = (const float*)d_in[1];
    const float* Wk = (const float*)d_in[2];
    const float* Wv = (const float*)d_in[3];
    const float* hw = (const float*)d_in[4];
    const float* Wu = (const float*)d_in[5];
    const float* bu = (const float*)d_in[6];
    float* out = (float*)d_out;

    const size_t MD = (size_t)MROWS * DMODEL;   // 4M elems
    const size_t WN = (size_t)DMODEL * DMODEL;  // 1M elems
    dim3 blk(THREADS);

    // workspace layout (all bf16/ushort): 56 MB total
    unsigned short* xh  = (unsigned short*)d_ws;  // 4M
    unsigned short* xl  = xh + MD;                // 4M
    unsigned short* wqh = xl + MD;                // 8 x 1M
    unsigned short* wql = wqh + WN;
    unsigned short* wkh = wql + WN;
    unsigned short* wkl = wkh + WN;
    unsigned short* wvh = wkl + WN;
    unsigned short* wvl = wvh + WN;
    unsigned short* wuh = wvl + WN;
    unsigned short* wul = wuh + WN;
    unsigned short* q_bf  = wul + WN;             // 4M  [b,h,s,hd]
    unsigned short* k_bf  = q_bf + MD;            // 4M  [b,h,s,hd]
    unsigned short* vt_bf = k_bf + MD;            // 4M  [b,h,hd,s]
    unsigned short* a_hi = xh;  // alias: x splits dead after gemm_qkv
    unsigned short* a_lo = xl;

    split_all<<<dim3(4096), blk, 0, stream>>>(x, Wq, Wk, Wv, Wu,
        xh, xl, wqh, wql, wkh, wkl, wvh, wvl, wuh, wul);
    gemm_qkv_mfma<<<dim3(NHEADS, MROWS / 128, 3), blk, 0, stream>>>(
        xh, xl, wqh, wql, wkh, wkl, wvh, wvl, q_bf, k_bf, vt_bf);
    attn_mfma<<<dim3(512), blk, 0, stream>>>(q_bf, k_bf, vt_bf, hw, a_hi, a_lo);
    gemm_out_mfma<<<dim3(DMODEL / 128, MROWS / 128), blk, 0, stream>>>(
        a_hi, a_lo, wuh, wul, bu, out);
}